// Round 7
// baseline (572.844 us; speedup 1.0000x reference)
//
#include <hip/hip_runtime.h>
#include <hip/hip_fp16.h>

// Problem constants (match reference)
#define IN_CH   128
#define HC      64      // channels per node at every layer boundary
#define NEG_SLOPE 0.2f

// counting-sort parameters: bucket = dst >> BSH (<=256 buckets), src in low 17 bits
#define BSH   9
#define NPB   512       // nodes per bucket = 1 << BSH
#define EPB   8192      // edges per binning block

// ---------------------------------------------------------------------------
// generic block scan kernels (used for the bucket-major countsT scan)
// ---------------------------------------------------------------------------
__global__ __launch_bounds__(256) void scan1_k(const int* __restrict__ deg, int* __restrict__ tmp,
                                               int* __restrict__ bsum, int n) {
    __shared__ int s[256];
    int tid = threadIdx.x;
    int i = blockIdx.x * 256 + tid;
    int v = (i < n) ? deg[i] : 0;
    s[tid] = v; __syncthreads();
    for (int o = 1; o < 256; o <<= 1) {
        int t = (tid >= o) ? s[tid - o] : 0;
        __syncthreads();
        s[tid] += t;
        __syncthreads();
    }
    if (i < n) tmp[i] = s[tid] - v;            // exclusive within block
    if (tid == 255) bsum[blockIdx.x] = s[255]; // block total
}

__global__ __launch_bounds__(512) void scan2_k(int* __restrict__ bsum, int nb) {
    __shared__ int s[512];
    int tid = threadIdx.x;
    int v = (tid < nb) ? bsum[tid] : 0;
    s[tid] = v; __syncthreads();
    for (int o = 1; o < 512; o <<= 1) {
        int t = (tid >= o) ? s[tid - o] : 0;
        __syncthreads();
        s[tid] += t;
        __syncthreads();
    }
    if (tid < nb) bsum[tid] = s[tid] - v;      // exclusive block offsets
}

__global__ __launch_bounds__(256) void combine_k(const int* __restrict__ tmp, const int* __restrict__ bsum,
                                                 int* __restrict__ base, int n) {
    int i = blockIdx.x * 256 + threadIdx.x;
    if (i < n) base[i] = tmp[i] + bsum[blockIdx.x];
}

// ---------------------------------------------------------------------------
// counting sort of edges by dst bucket — LDS-binned, no global atomic contention
// ---------------------------------------------------------------------------
__global__ __launch_bounds__(256) void csortA1_k(const int* __restrict__ ei, int* __restrict__ countsT,
                                                 int E, int nbuck, int neb) {
    __shared__ int cnt[256];
    cnt[threadIdx.x] = 0;
    __syncthreads();
    int base = blockIdx.x * EPB;
#pragma unroll
    for (int k = 0; k < EPB / 256; k++) {
        int i = base + k * 256 + threadIdx.x;
        if (i < E) atomicAdd(&cnt[ei[E + i] >> BSH], 1);
    }
    __syncthreads();
    if (threadIdx.x < nbuck) countsT[threadIdx.x * neb + blockIdx.x] = cnt[threadIdx.x];
}

__global__ __launch_bounds__(256) void csortA3_k(const int* __restrict__ ei, const int* __restrict__ baseT,
                                                 unsigned* __restrict__ pairs, int E, int nbuck, int neb) {
    __shared__ int cur[256];
    if (threadIdx.x < nbuck) cur[threadIdx.x] = baseT[threadIdx.x * neb + blockIdx.x];
    __syncthreads();
    int base = blockIdx.x * EPB;
#pragma unroll
    for (int k = 0; k < EPB / 256; k++) {
        int i = base + k * 256 + threadIdx.x;
        if (i < E) {
            int d = ei[E + i];
            int s = ei[i];
            int p = atomicAdd(&cur[d >> BSH], 1);
            pairs[p] = ((unsigned)(d & (NPB - 1)) << 17) | (unsigned)s;
        }
    }
}

// B: one block per bucket. Fused: per-node LDS histogram -> block scan ->
// node offsets (off[]) -> LDS-cursor ranking -> csr write.
__global__ __launch_bounds__(256) void csortB2_k(const unsigned* __restrict__ pairs, const int* __restrict__ baseT,
                                                 int* __restrict__ off, int* __restrict__ csr,
                                                 int N, int E, int nbuck, int neb) {
    __shared__ int cnt[NPB];
    __shared__ int cur[NPB];
    __shared__ int ps[256];
    int b = blockIdx.x;
    int tid = threadIdx.x;
    int rs = baseT[b * neb];
    int re = (b + 1 < nbuck) ? baseT[(b + 1) * neb] : E;

    cnt[tid] = 0; cnt[tid + 256] = 0;
    __syncthreads();
    for (int j = rs + tid; j < re; j += 256)
        atomicAdd(&cnt[pairs[j] >> 17], 1);
    __syncthreads();

    int c0 = cnt[2 * tid], c1 = cnt[2 * tid + 1];
    int pair = c0 + c1;
    ps[tid] = pair;
    __syncthreads();
    for (int o = 1; o < 256; o <<= 1) {
        int t = (tid >= o) ? ps[tid - o] : 0;
        __syncthreads();
        ps[tid] += t;
        __syncthreads();
    }
    int base0 = rs + ps[tid] - pair;
    int n0 = b * NPB + 2 * tid;
    cur[2 * tid] = base0;
    cur[2 * tid + 1] = base0 + c0;
    if (n0 < N)     off[n0] = base0;
    if (n0 + 1 < N) off[n0 + 1] = base0 + c0;
    if (b == nbuck - 1 && tid == 0) off[N] = E;
    __syncthreads();

    for (int j = rs + tid; j < re; j += 256) {
        unsigned v = pairs[j];
        int p = atomicAdd(&cur[v >> 17], 1);
        csr[p] = (int)(v & 0x1FFFF);
    }
}

// ---------------------------------------------------------------------------
// GEMM  H[n,64] = X[n,K] @ W[K,64]  + fused attention-logit epilogue.
// LANE = ROW; W staged in LDS; acc as 16 float4, launch_bounds(256,1).
// ---------------------------------------------------------------------------
template<int K, int HEADS>
__global__ __launch_bounds__(256, 1) void gemm_al_k(const float* __restrict__ X, const float* __restrict__ W,
                                                    const float* __restrict__ a_s, const float* __restrict__ a_d,
                                                    __half* __restrict__ H, float* __restrict__ ALS,
                                                    float* __restrict__ ALD, int n) {
    __shared__ float4 lw[K * 16];
    int tid = threadIdx.x;
    const float4* wv = (const float4*)W;
#pragma unroll
    for (int j = 0; j < K * 16 / 256; j++)
        lw[tid + 256 * j] = wv[tid + 256 * j];
    __syncthreads();

    int row = blockIdx.x * 256 + tid;
    if (row >= n) return;

    float4 acc[16];
#pragma unroll
    for (int c4 = 0; c4 < 16; c4++) acc[c4] = make_float4(0.f, 0.f, 0.f, 0.f);

    const float4* xv = (const float4*)(X + (size_t)row * K);
    float4 xx = xv[0];
#pragma unroll 1
    for (int k4 = 0; k4 < K / 4; k4++) {
        float4 xn = make_float4(0.f, 0.f, 0.f, 0.f);
        if (k4 + 1 < K / 4) xn = xv[k4 + 1];          // prefetch next X chunk
#pragma unroll
        for (int j = 0; j < 4; j++) {
            float xs = (j == 0) ? xx.x : (j == 1) ? xx.y : (j == 2) ? xx.z : xx.w;
            const float4* wr = &lw[(k4 * 4 + j) * 16]; // wave-uniform LDS row
#pragma unroll
            for (int c4 = 0; c4 < 16; c4++) {
                float4 w = wr[c4];
                acc[c4].x += xs * w.x;
                acc[c4].y += xs * w.y;
                acc[c4].z += xs * w.z;
                acc[c4].w += xs * w.w;
            }
        }
        xx = xn;
    }

    if (HEADS == 2) {
        float s0 = 0.f, d0 = 0.f, s1 = 0.f, d1 = 0.f;
#pragma unroll
        for (int c4 = 0; c4 < 8; c4++) {
            s0 += acc[c4].x * a_s[4 * c4]     + acc[c4].y * a_s[4 * c4 + 1]
                + acc[c4].z * a_s[4 * c4 + 2] + acc[c4].w * a_s[4 * c4 + 3];
            d0 += acc[c4].x * a_d[4 * c4]     + acc[c4].y * a_d[4 * c4 + 1]
                + acc[c4].z * a_d[4 * c4 + 2] + acc[c4].w * a_d[4 * c4 + 3];
            s1 += acc[8 + c4].x * a_s[32 + 4 * c4]     + acc[8 + c4].y * a_s[32 + 4 * c4 + 1]
                + acc[8 + c4].z * a_s[32 + 4 * c4 + 2] + acc[8 + c4].w * a_s[32 + 4 * c4 + 3];
            d1 += acc[8 + c4].x * a_d[32 + 4 * c4]     + acc[8 + c4].y * a_d[32 + 4 * c4 + 1]
                + acc[8 + c4].z * a_d[32 + 4 * c4 + 2] + acc[8 + c4].w * a_d[32 + 4 * c4 + 3];
        }
        ALS[(size_t)row * 2]     = s0;
        ALS[(size_t)row * 2 + 1] = s1;
        ALD[(size_t)row * 2]     = d0;
        ALD[(size_t)row * 2 + 1] = d1;
    } else {
        float s0 = 0.f, d0 = 0.f;
#pragma unroll
        for (int c4 = 0; c4 < 16; c4++) {
            s0 += acc[c4].x * a_s[4 * c4]     + acc[c4].y * a_s[4 * c4 + 1]
                + acc[c4].z * a_s[4 * c4 + 2] + acc[c4].w * a_s[4 * c4 + 3];
            d0 += acc[c4].x * a_d[4 * c4]     + acc[c4].y * a_d[4 * c4 + 1]
                + acc[c4].z * a_d[4 * c4 + 2] + acc[c4].w * a_d[4 * c4 + 3];
        }
        ALS[row] = s0;
        ALD[row] = d0;
    }

    uint4* hv = (uint4*)(H + (size_t)row * 64);
#pragma unroll
    for (int c8 = 0; c8 < 8; c8++) {
        __half2 p0 = __floats2half2_rn(acc[2 * c8].x, acc[2 * c8].y);
        __half2 p1 = __floats2half2_rn(acc[2 * c8].z, acc[2 * c8].w);
        __half2 p2 = __floats2half2_rn(acc[2 * c8 + 1].x, acc[2 * c8 + 1].y);
        __half2 p3 = __floats2half2_rn(acc[2 * c8 + 1].z, acc[2 * c8 + 1].w);
        uint4 u;
        u.x = *(unsigned*)&p0;
        u.y = *(unsigned*)&p1;
        u.z = *(unsigned*)&p2;
        u.w = *(unsigned*)&p3;
        hv[c8] = u;
    }
}

// ---------------------------------------------------------------------------
// Edge-weight precompute: ONE THREAD PER DST NODE (no 64-lane redundancy).
// Computes w[i]=exp(leaky(ALS[src]+ALD[dst])) aligned to csr order, plus
// per-node self-weight and reciprocal softmax denominator.
// ---------------------------------------------------------------------------
template<int HEADS>
__global__ __launch_bounds__(256) void edgew_k(const float* __restrict__ ALS, const float* __restrict__ ALD,
                                               const int* __restrict__ off, const int* __restrict__ csr,
                                               float* __restrict__ Wg, float* __restrict__ SW,
                                               float* __restrict__ RD, int n) {
    int d = blockIdx.x * 256 + threadIdx.x;
    if (d >= n) return;
    int b0 = off[d], b1 = off[d + 1];
    if (HEADS == 2) {
        float2 ad = ((const float2*)ALD)[d];
        float2 as = ((const float2*)ALS)[d];
        float e0 = as.x + ad.x; e0 = (e0 >= 0.f) ? e0 : NEG_SLOPE * e0;
        float e1 = as.y + ad.y; e1 = (e1 >= 0.f) ? e1 : NEG_SLOPE * e1;
        float w0 = __expf(e0), w1 = __expf(e1);
        ((float2*)SW)[d] = make_float2(w0, w1);
        float den0 = w0, den1 = w1;
#pragma unroll 2
        for (int i = b0; i < b1; i++) {
            int s = csr[i];
            float2 a = ((const float2*)ALS)[s];
            float f0 = a.x + ad.x; f0 = (f0 >= 0.f) ? f0 : NEG_SLOPE * f0;
            float f1 = a.y + ad.y; f1 = (f1 >= 0.f) ? f1 : NEG_SLOPE * f1;
            float v0 = __expf(f0), v1 = __expf(f1);
            ((float2*)Wg)[i] = make_float2(v0, v1);
            den0 += v0; den1 += v1;
        }
        ((float2*)RD)[d] = make_float2(1.f / den0, 1.f / den1);
    } else {
        float ad = ALD[d];
        float e0 = ALS[d] + ad; e0 = (e0 >= 0.f) ? e0 : NEG_SLOPE * e0;
        float w0 = __expf(e0);
        SW[d] = w0;
        float den0 = w0;
#pragma unroll 2
        for (int i = b0; i < b1; i++) {
            int s = csr[i];
            float f0 = ALS[s] + ad; f0 = (f0 >= 0.f) ? f0 : NEG_SLOPE * f0;
            float v0 = __expf(f0);
            Wg[i] = v0;
            den0 += v0;
        }
        RD[d] = 1.f / den0;
    }
}

// ---------------------------------------------------------------------------
// Aggregation: one wave per dst node, lane = channel. Pure weighted gather:
// per edge = uniform w load + fp16 H-row gather + 1 FMA per lane.
// ---------------------------------------------------------------------------
template<int HEADS, int RELU>
__global__ __launch_bounds__(256) void aggregate_k(const __half* __restrict__ H, const float* __restrict__ Wg,
                                                   const float* __restrict__ SW, const float* __restrict__ RD,
                                                   const int* __restrict__ off, const int* __restrict__ csr,
                                                   const float* __restrict__ bias, float* __restrict__ OUT, int n) {
    int lane = threadIdx.x & 63;
    int dst = (blockIdx.x << 2) + (threadIdx.x >> 6);
    if (dst >= n) return;
    int head = (HEADS == 2) ? (lane >> 5) : 0;
    const __half* Hl = H + lane;

    float sw, rd;
    if (HEADS == 2) {
        float2 s2 = ((const float2*)SW)[dst];
        float2 r2 = ((const float2*)RD)[dst];
        sw = head ? s2.y : s2.x;
        rd = head ? r2.y : r2.x;
    } else {
        sw = SW[dst];
        rd = RD[dst];
    }
    float acc = sw * __half2float(Hl[(size_t)dst * 64]);

    int b0 = off[dst], b1 = off[dst + 1];
    int i = b0;
    for (; i + 3 < b1; i += 4) {
        int s0 = csr[i], s1 = csr[i + 1], s2 = csr[i + 2], s3 = csr[i + 3];
        float w0, w1, w2, w3;
        if (HEADS == 2) {
            float2 a = ((const float2*)Wg)[i];
            float2 b = ((const float2*)Wg)[i + 1];
            float2 c = ((const float2*)Wg)[i + 2];
            float2 d = ((const float2*)Wg)[i + 3];
            w0 = head ? a.y : a.x; w1 = head ? b.y : b.x;
            w2 = head ? c.y : c.x; w3 = head ? d.y : d.x;
        } else {
            w0 = Wg[i]; w1 = Wg[i + 1]; w2 = Wg[i + 2]; w3 = Wg[i + 3];
        }
        float h0 = __half2float(Hl[(size_t)s0 * 64]);
        float h1 = __half2float(Hl[(size_t)s1 * 64]);
        float h2 = __half2float(Hl[(size_t)s2 * 64]);
        float h3 = __half2float(Hl[(size_t)s3 * 64]);
        acc += (w0 * h0 + w1 * h1) + (w2 * h2 + w3 * h3);
    }
    for (; i < b1; i++) {
        int s0 = csr[i];
        float w0;
        if (HEADS == 2) {
            float2 a = ((const float2*)Wg)[i];
            w0 = head ? a.y : a.x;
        } else {
            w0 = Wg[i];
        }
        acc += w0 * __half2float(Hl[(size_t)s0 * 64]);
    }

    float o = acc * rd + bias[lane];
    if (RELU) o = (o > 0.f) ? o : 0.f;
    OUT[(size_t)dst * 64 + lane] = o;
}

// ---------------------------------------------------------------------------
extern "C" void kernel_launch(void* const* d_in, const int* in_sizes, int n_in,
                              void* d_out, int out_size, void* d_ws, size_t ws_size,
                              hipStream_t stream) {
    const float* x   = (const float*)d_in[0];
    const int*   ei  = (const int*)  d_in[1];
    const float* W1  = (const float*)d_in[2];
    const float* as1 = (const float*)d_in[3];
    const float* ad1 = (const float*)d_in[4];
    const float* b1  = (const float*)d_in[5];
    const float* W2  = (const float*)d_in[6];
    const float* as2 = (const float*)d_in[7];
    const float* ad2 = (const float*)d_in[8];
    const float* b2  = (const float*)d_in[9];
    const float* W3  = (const float*)d_in[10];
    const float* as3 = (const float*)d_in[11];
    const float* ad3 = (const float*)d_in[12];
    const float* b3  = (const float*)d_in[13];

    const int N = in_sizes[0] / IN_CH;
    const int E = in_sizes[1] / 2;
    const int NBUCK = (N + NPB - 1) >> BSH;              // 196 (<=256)
    const int NEB   = (E + EPB - 1) / EPB;               // 196 binning blocks
    const int NT    = NBUCK * NEB;                       // countsT elements (~38k)

    // workspace carve (256B aligned)
    char* p = (char*)d_ws;
    auto carve = [&](size_t bytes) {
        char* r = p;
        p += (bytes + 255) & ~(size_t)255;
        return r;
    };
    __half*   hbuf    = (__half*)  carve((size_t)N * HC * 2);
    float*    obuf    = (float*)   carve((size_t)N * HC * 4);
    float*    als     = (float*)   carve((size_t)N * 2 * 4);
    float*    ald     = (float*)   carve((size_t)N * 2 * 4);
    float*    ew      = (float*)   carve((size_t)E * 2 * 4);   // per-edge weights (2 heads)
    float*    swb     = (float*)   carve((size_t)N * 2 * 4);   // self weights
    float*    rdb     = (float*)   carve((size_t)N * 2 * 4);   // reciprocal denominators
    int*      off     = (int*)     carve((size_t)(N + 1) * 4);
    int*      tmp     = (int*)     carve((size_t)NT * 4);
    int*      bsum    = (int*)     carve((size_t)((NT + 255) / 256 + 1) * 4);
    int*      csr     = (int*)     carve((size_t)E * 4);
    unsigned* pairs   = (unsigned*)carve((size_t)E * 4);
    int*      countsT = (int*)     carve((size_t)NT * 4);
    int*      baseT   = (int*)     carve((size_t)NT * 4);

    const int NB  = (N + 255) / 256;      // node-parallel blocks
    const int NTB = (NT + 255) / 256;     // countsT-scan blocks (<=512)
    const int NW  = (N + 3) / 4;          // aggregate: one wave per node, 4 waves/block

    // ---- CSR build (shared by all 3 layers); off[] fused into pass B ----
    csortA1_k<<<NEB, 256, 0, stream>>>(ei, countsT, E, NBUCK, NEB);
    scan1_k  <<<NTB, 256, 0, stream>>>(countsT, tmp, bsum, NT);
    scan2_k  <<<1, 512, 0, stream>>>(bsum, NTB);
    combine_k<<<NTB, 256, 0, stream>>>(tmp, bsum, baseT, NT);
    csortA3_k<<<NEB, 256, 0, stream>>>(ei, baseT, pairs, E, NBUCK, NEB);
    csortB2_k<<<NBUCK, 256, 0, stream>>>(pairs, baseT, off, csr, N, E, NBUCK, NEB);

    // ---- Layer 1: IN=128 -> 2x32 concat, relu ----
    gemm_al_k<128, 2><<<NB, 256, 0, stream>>>(x, W1, as1, ad1, hbuf, als, ald, N);
    edgew_k<2>       <<<NB, 256, 0, stream>>>(als, ald, off, csr, ew, swb, rdb, N);
    aggregate_k<2, 1><<<NW, 256, 0, stream>>>(hbuf, ew, swb, rdb, off, csr, b1, obuf, N);

    // ---- Layer 2: 64 -> 2x32 concat, relu ----
    gemm_al_k<64, 2><<<NB, 256, 0, stream>>>(obuf, W2, as2, ad2, hbuf, als, ald, N);
    edgew_k<2>      <<<NB, 256, 0, stream>>>(als, ald, off, csr, ew, swb, rdb, N);
    aggregate_k<2, 1><<<NW, 256, 0, stream>>>(hbuf, ew, swb, rdb, off, csr, b2, obuf, N);

    // ---- Layer 3: 64 -> 64, 1 head, mean(=identity), no relu ----
    gemm_al_k<64, 1><<<NB, 256, 0, stream>>>(obuf, W3, as3, ad3, hbuf, als, ald, N);
    edgew_k<1>      <<<NB, 256, 0, stream>>>(als, ald, off, csr, ew, swb, rdb, N);
    aggregate_k<1, 0><<<NW, 256, 0, stream>>>(hbuf, ew, swb, rdb, off, csr, b3, (float*)d_out, N);
}

// Round 8
// 462.893 us; speedup vs baseline: 1.2375x; 1.2375x over previous
//
#include <hip/hip_runtime.h>
#include <hip/hip_fp16.h>

// Problem constants (match reference)
#define IN_CH   128
#define HC      64      // channels per node at every layer boundary
#define NEG_SLOPE 0.2f

// counting-sort parameters: bucket = dst >> BSH (<=256 buckets), src in low 17 bits
#define BSH   9
#define NPB   512       // nodes per bucket = 1 << BSH
#define EPB   8192      // edges per binning block

// ---------------------------------------------------------------------------
// generic block scan kernels (used for the bucket-major countsT scan)
// ---------------------------------------------------------------------------
__global__ __launch_bounds__(256) void scan1_k(const int* __restrict__ deg, int* __restrict__ tmp,
                                               int* __restrict__ bsum, int n) {
    __shared__ int s[256];
    int tid = threadIdx.x;
    int i = blockIdx.x * 256 + tid;
    int v = (i < n) ? deg[i] : 0;
    s[tid] = v; __syncthreads();
    for (int o = 1; o < 256; o <<= 1) {
        int t = (tid >= o) ? s[tid - o] : 0;
        __syncthreads();
        s[tid] += t;
        __syncthreads();
    }
    if (i < n) tmp[i] = s[tid] - v;            // exclusive within block
    if (tid == 255) bsum[blockIdx.x] = s[255]; // block total
}

__global__ __launch_bounds__(512) void scan2_k(int* __restrict__ bsum, int nb) {
    __shared__ int s[512];
    int tid = threadIdx.x;
    int v = (tid < nb) ? bsum[tid] : 0;
    s[tid] = v; __syncthreads();
    for (int o = 1; o < 512; o <<= 1) {
        int t = (tid >= o) ? s[tid - o] : 0;
        __syncthreads();
        s[tid] += t;
        __syncthreads();
    }
    if (tid < nb) bsum[tid] = s[tid] - v;      // exclusive block offsets
}

__global__ __launch_bounds__(256) void combine_k(const int* __restrict__ tmp, const int* __restrict__ bsum,
                                                 int* __restrict__ base, int n) {
    int i = blockIdx.x * 256 + threadIdx.x;
    if (i < n) base[i] = tmp[i] + bsum[blockIdx.x];
}

// ---------------------------------------------------------------------------
// counting sort of edges by dst bucket — LDS-binned, no global atomic contention
// ---------------------------------------------------------------------------
__global__ __launch_bounds__(256) void csortA1_k(const int* __restrict__ ei, int* __restrict__ countsT,
                                                 int E, int nbuck, int neb) {
    __shared__ int cnt[256];
    cnt[threadIdx.x] = 0;
    __syncthreads();
    int base = blockIdx.x * EPB;
#pragma unroll
    for (int k = 0; k < EPB / 256; k++) {
        int i = base + k * 256 + threadIdx.x;
        if (i < E) atomicAdd(&cnt[ei[E + i] >> BSH], 1);
    }
    __syncthreads();
    if (threadIdx.x < nbuck) countsT[threadIdx.x * neb + blockIdx.x] = cnt[threadIdx.x];
}

__global__ __launch_bounds__(256) void csortA3_k(const int* __restrict__ ei, const int* __restrict__ baseT,
                                                 unsigned* __restrict__ pairs, int E, int nbuck, int neb) {
    __shared__ int cur[256];
    if (threadIdx.x < nbuck) cur[threadIdx.x] = baseT[threadIdx.x * neb + blockIdx.x];
    __syncthreads();
    int base = blockIdx.x * EPB;
#pragma unroll
    for (int k = 0; k < EPB / 256; k++) {
        int i = base + k * 256 + threadIdx.x;
        if (i < E) {
            int d = ei[E + i];
            int s = ei[i];
            int p = atomicAdd(&cur[d >> BSH], 1);
            pairs[p] = ((unsigned)(d & (NPB - 1)) << 17) | (unsigned)s;
        }
    }
}

// B: one block per bucket. Fused: per-node LDS histogram -> block scan ->
// node offsets (off[]) -> LDS-cursor ranking -> csr write.
__global__ __launch_bounds__(256) void csortB2_k(const unsigned* __restrict__ pairs, const int* __restrict__ baseT,
                                                 int* __restrict__ off, int* __restrict__ csr,
                                                 int N, int E, int nbuck, int neb) {
    __shared__ int cnt[NPB];
    __shared__ int cur[NPB];
    __shared__ int ps[256];
    int b = blockIdx.x;
    int tid = threadIdx.x;
    int rs = baseT[b * neb];
    int re = (b + 1 < nbuck) ? baseT[(b + 1) * neb] : E;

    cnt[tid] = 0; cnt[tid + 256] = 0;
    __syncthreads();
    for (int j = rs + tid; j < re; j += 256)
        atomicAdd(&cnt[pairs[j] >> 17], 1);
    __syncthreads();

    int c0 = cnt[2 * tid], c1 = cnt[2 * tid + 1];
    int pair = c0 + c1;
    ps[tid] = pair;
    __syncthreads();
    for (int o = 1; o < 256; o <<= 1) {
        int t = (tid >= o) ? ps[tid - o] : 0;
        __syncthreads();
        ps[tid] += t;
        __syncthreads();
    }
    int base0 = rs + ps[tid] - pair;
    int n0 = b * NPB + 2 * tid;
    cur[2 * tid] = base0;
    cur[2 * tid + 1] = base0 + c0;
    if (n0 < N)     off[n0] = base0;
    if (n0 + 1 < N) off[n0 + 1] = base0 + c0;
    if (b == nbuck - 1 && tid == 0) off[N] = E;
    __syncthreads();

    for (int j = rs + tid; j < re; j += 256) {
        unsigned v = pairs[j];
        int p = atomicAdd(&cur[v >> 17], 1);
        csr[p] = (int)(v & 0x1FFFF);
    }
}

// ---------------------------------------------------------------------------
// GEMM  H[n,64] = X[n,K] @ W[K,64]  + fused attention-logit epilogue.
// LANE = ROW; W staged in LDS; acc as 16 float4, launch_bounds(256,1).
// ---------------------------------------------------------------------------
template<int K, int HEADS>
__global__ __launch_bounds__(256, 1) void gemm_al_k(const float* __restrict__ X, const float* __restrict__ W,
                                                    const float* __restrict__ a_s, const float* __restrict__ a_d,
                                                    __half* __restrict__ H, float* __restrict__ ALS,
                                                    float* __restrict__ ALD, int n) {
    __shared__ float4 lw[K * 16];
    int tid = threadIdx.x;
    const float4* wv = (const float4*)W;
#pragma unroll
    for (int j = 0; j < K * 16 / 256; j++)
        lw[tid + 256 * j] = wv[tid + 256 * j];
    __syncthreads();

    int row = blockIdx.x * 256 + tid;
    if (row >= n) return;

    float4 acc[16];
#pragma unroll
    for (int c4 = 0; c4 < 16; c4++) acc[c4] = make_float4(0.f, 0.f, 0.f, 0.f);

    const float4* xv = (const float4*)(X + (size_t)row * K);
    float4 xx = xv[0];
#pragma unroll 1
    for (int k4 = 0; k4 < K / 4; k4++) {
        float4 xn = make_float4(0.f, 0.f, 0.f, 0.f);
        if (k4 + 1 < K / 4) xn = xv[k4 + 1];          // prefetch next X chunk
#pragma unroll
        for (int j = 0; j < 4; j++) {
            float xs = (j == 0) ? xx.x : (j == 1) ? xx.y : (j == 2) ? xx.z : xx.w;
            const float4* wr = &lw[(k4 * 4 + j) * 16]; // wave-uniform LDS row
#pragma unroll
            for (int c4 = 0; c4 < 16; c4++) {
                float4 w = wr[c4];
                acc[c4].x += xs * w.x;
                acc[c4].y += xs * w.y;
                acc[c4].z += xs * w.z;
                acc[c4].w += xs * w.w;
            }
        }
        xx = xn;
    }

    if (HEADS == 2) {
        float s0 = 0.f, d0 = 0.f, s1 = 0.f, d1 = 0.f;
#pragma unroll
        for (int c4 = 0; c4 < 8; c4++) {
            s0 += acc[c4].x * a_s[4 * c4]     + acc[c4].y * a_s[4 * c4 + 1]
                + acc[c4].z * a_s[4 * c4 + 2] + acc[c4].w * a_s[4 * c4 + 3];
            d0 += acc[c4].x * a_d[4 * c4]     + acc[c4].y * a_d[4 * c4 + 1]
                + acc[c4].z * a_d[4 * c4 + 2] + acc[c4].w * a_d[4 * c4 + 3];
            s1 += acc[8 + c4].x * a_s[32 + 4 * c4]     + acc[8 + c4].y * a_s[32 + 4 * c4 + 1]
                + acc[8 + c4].z * a_s[32 + 4 * c4 + 2] + acc[8 + c4].w * a_s[32 + 4 * c4 + 3];
            d1 += acc[8 + c4].x * a_d[32 + 4 * c4]     + acc[8 + c4].y * a_d[32 + 4 * c4 + 1]
                + acc[8 + c4].z * a_d[32 + 4 * c4 + 2] + acc[8 + c4].w * a_d[32 + 4 * c4 + 3];
        }
        ALS[(size_t)row * 2]     = s0;
        ALS[(size_t)row * 2 + 1] = s1;
        ALD[(size_t)row * 2]     = d0;
        ALD[(size_t)row * 2 + 1] = d1;
    } else {
        float s0 = 0.f, d0 = 0.f;
#pragma unroll
        for (int c4 = 0; c4 < 16; c4++) {
            s0 += acc[c4].x * a_s[4 * c4]     + acc[c4].y * a_s[4 * c4 + 1]
                + acc[c4].z * a_s[4 * c4 + 2] + acc[c4].w * a_s[4 * c4 + 3];
            d0 += acc[c4].x * a_d[4 * c4]     + acc[c4].y * a_d[4 * c4 + 1]
                + acc[c4].z * a_d[4 * c4 + 2] + acc[c4].w * a_d[4 * c4 + 3];
        }
        ALS[row] = s0;
        ALD[row] = d0;
    }

    uint4* hv = (uint4*)(H + (size_t)row * 64);
#pragma unroll
    for (int c8 = 0; c8 < 8; c8++) {
        __half2 p0 = __floats2half2_rn(acc[2 * c8].x, acc[2 * c8].y);
        __half2 p1 = __floats2half2_rn(acc[2 * c8].z, acc[2 * c8].w);
        __half2 p2 = __floats2half2_rn(acc[2 * c8 + 1].x, acc[2 * c8 + 1].y);
        __half2 p3 = __floats2half2_rn(acc[2 * c8 + 1].z, acc[2 * c8 + 1].w);
        uint4 u;
        u.x = *(unsigned*)&p0;
        u.y = *(unsigned*)&p1;
        u.z = *(unsigned*)&p2;
        u.w = *(unsigned*)&p3;
        hv[c8] = u;
    }
}

// ---------------------------------------------------------------------------
// Aggregation: one wave per dst node, lane = channel. Atomic-free, fused
// softmax (exp recomputed in-wave: SIMT makes lane-redundancy free).
// 8-way unrolled edge loop: 8 independent H-row gathers in flight per iter.
// ---------------------------------------------------------------------------
template<int HEADS, int RELU>
__global__ __launch_bounds__(256) void aggregate_k(const __half* __restrict__ H, const float* __restrict__ ALS,
                                                   const float* __restrict__ ALD, const int* __restrict__ off,
                                                   const int* __restrict__ csr, const float* __restrict__ bias,
                                                   float* __restrict__ OUT, int n) {
    int lane = threadIdx.x & 63;
    int dst = (blockIdx.x << 2) + (threadIdx.x >> 6);
    if (dst >= n) return;
    int head = (HEADS == 2) ? (lane >> 5) : 0;
    float ald = ALD[(size_t)dst * HEADS + head];
    const __half* Hl = H + lane;

    // self-loop contribution
    float e = ALS[(size_t)dst * HEADS + head] + ald;
    e = (e >= 0.f) ? e : NEG_SLOPE * e;
    float ee = __expf(e);
    float den = ee;
    float acc = ee * __half2float(Hl[(size_t)dst * 64]);

    int b0 = off[dst], b1 = off[dst + 1];
    int i = b0;
    for (; i + 7 < b1; i += 8) {
        int s[8];
#pragma unroll
        for (int j = 0; j < 8; j++) s[j] = csr[i + j];
        float al[8], h[8];
#pragma unroll
        for (int j = 0; j < 8; j++) al[j] = ALS[(size_t)s[j] * HEADS + head];
#pragma unroll
        for (int j = 0; j < 8; j++) h[j] = __half2float(Hl[(size_t)s[j] * 64]);
#pragma unroll
        for (int j = 0; j < 8; j++) {
            float ej = al[j] + ald;
            ej = (ej >= 0.f) ? ej : NEG_SLOPE * ej;
            float wj = __expf(ej);
            den += wj;
            acc += wj * h[j];
        }
    }
    for (; i + 3 < b1; i += 4) {
        int s0 = csr[i], s1 = csr[i + 1], s2 = csr[i + 2], s3 = csr[i + 3];
        float e0 = ALS[(size_t)s0 * HEADS + head] + ald;
        float e1 = ALS[(size_t)s1 * HEADS + head] + ald;
        float e2 = ALS[(size_t)s2 * HEADS + head] + ald;
        float e3 = ALS[(size_t)s3 * HEADS + head] + ald;
        float h0 = __half2float(Hl[(size_t)s0 * 64]);
        float h1 = __half2float(Hl[(size_t)s1 * 64]);
        float h2 = __half2float(Hl[(size_t)s2 * 64]);
        float h3 = __half2float(Hl[(size_t)s3 * 64]);
        e0 = (e0 >= 0.f) ? e0 : NEG_SLOPE * e0;
        e1 = (e1 >= 0.f) ? e1 : NEG_SLOPE * e1;
        e2 = (e2 >= 0.f) ? e2 : NEG_SLOPE * e2;
        e3 = (e3 >= 0.f) ? e3 : NEG_SLOPE * e3;
        float w0 = __expf(e0);
        float w1 = __expf(e1);
        float w2 = __expf(e2);
        float w3 = __expf(e3);
        den += (w0 + w1) + (w2 + w3);
        acc += (w0 * h0 + w1 * h1) + (w2 * h2 + w3 * h3);
    }
    for (; i < b1; i++) {
        int s0 = csr[i];
        float e0 = ALS[(size_t)s0 * HEADS + head] + ald;
        e0 = (e0 >= 0.f) ? e0 : NEG_SLOPE * e0;
        float w0 = __expf(e0);
        den += w0;
        acc += w0 * __half2float(Hl[(size_t)s0 * 64]);
    }

    float o = acc / den + bias[lane];
    if (RELU) o = (o > 0.f) ? o : 0.f;
    OUT[(size_t)dst * 64 + lane] = o;
}

// ---------------------------------------------------------------------------
extern "C" void kernel_launch(void* const* d_in, const int* in_sizes, int n_in,
                              void* d_out, int out_size, void* d_ws, size_t ws_size,
                              hipStream_t stream) {
    const float* x   = (const float*)d_in[0];
    const int*   ei  = (const int*)  d_in[1];
    const float* W1  = (const float*)d_in[2];
    const float* as1 = (const float*)d_in[3];
    const float* ad1 = (const float*)d_in[4];
    const float* b1  = (const float*)d_in[5];
    const float* W2  = (const float*)d_in[6];
    const float* as2 = (const float*)d_in[7];
    const float* ad2 = (const float*)d_in[8];
    const float* b2  = (const float*)d_in[9];
    const float* W3  = (const float*)d_in[10];
    const float* as3 = (const float*)d_in[11];
    const float* ad3 = (const float*)d_in[12];
    const float* b3  = (const float*)d_in[13];

    const int N = in_sizes[0] / IN_CH;
    const int E = in_sizes[1] / 2;
    const int NBUCK = (N + NPB - 1) >> BSH;              // 196 (<=256)
    const int NEB   = (E + EPB - 1) / EPB;               // 196 binning blocks
    const int NT    = NBUCK * NEB;                       // countsT elements (~38k)

    // workspace carve (256B aligned)
    char* p = (char*)d_ws;
    auto carve = [&](size_t bytes) {
        char* r = p;
        p += (bytes + 255) & ~(size_t)255;
        return r;
    };
    __half*   hbuf    = (__half*)  carve((size_t)N * HC * 2);
    float*    obuf    = (float*)   carve((size_t)N * HC * 4);
    float*    als     = (float*)   carve((size_t)N * 2 * 4);
    float*    ald     = (float*)   carve((size_t)N * 2 * 4);
    int*      off     = (int*)     carve((size_t)(N + 1) * 4);
    int*      tmp     = (int*)     carve((size_t)NT * 4);
    int*      bsum    = (int*)     carve((size_t)((NT + 255) / 256 + 1) * 4);
    int*      csr     = (int*)     carve((size_t)E * 4);
    unsigned* pairs   = (unsigned*)carve((size_t)E * 4);
    int*      countsT = (int*)     carve((size_t)NT * 4);
    int*      baseT   = (int*)     carve((size_t)NT * 4);

    const int NB  = (N + 255) / 256;      // node-parallel blocks
    const int NTB = (NT + 255) / 256;     // countsT-scan blocks (<=512)
    const int NW  = (N + 3) / 4;          // aggregate: one wave per node, 4 waves/block

    // ---- CSR build (shared by all 3 layers); off[] fused into pass B ----
    csortA1_k<<<NEB, 256, 0, stream>>>(ei, countsT, E, NBUCK, NEB);
    scan1_k  <<<NTB, 256, 0, stream>>>(countsT, tmp, bsum, NT);
    scan2_k  <<<1, 512, 0, stream>>>(bsum, NTB);
    combine_k<<<NTB, 256, 0, stream>>>(tmp, bsum, baseT, NT);
    csortA3_k<<<NEB, 256, 0, stream>>>(ei, baseT, pairs, E, NBUCK, NEB);
    csortB2_k<<<NBUCK, 256, 0, stream>>>(pairs, baseT, off, csr, N, E, NBUCK, NEB);

    // ---- Layer 1: IN=128 -> 2x32 concat, relu ----
    gemm_al_k<128, 2><<<NB, 256, 0, stream>>>(x, W1, as1, ad1, hbuf, als, ald, N);
    aggregate_k<2, 1><<<NW, 256, 0, stream>>>(hbuf, als, ald, off, csr, b1, obuf, N);

    // ---- Layer 2: 64 -> 2x32 concat, relu ----
    gemm_al_k<64, 2><<<NB, 256, 0, stream>>>(obuf, W2, as2, ad2, hbuf, als, ald, N);
    aggregate_k<2, 1><<<NW, 256, 0, stream>>>(hbuf, als, ald, off, csr, b2, obuf, N);

    // ---- Layer 3: 64 -> 64, 1 head, mean(=identity), no relu ----
    gemm_al_k<64, 1><<<NB, 256, 0, stream>>>(obuf, W3, as3, ad3, hbuf, als, ald, N);
    aggregate_k<1, 0><<<NW, 256, 0, stream>>>(hbuf, als, ald, off, csr, b3, (float*)d_out, N);
}